// Round 8
// baseline (4313.464 us; speedup 1.0000x reference)
//
#include <hip/hip_runtime.h>

// TransformerDecoder scan: B=128 independent sequences, one workgroup each,
// 8 waves/WG. FFN is swapped-operand MFMA (h^T = W1·X^T) so the 2048-wide
// hidden activation stays entirely in registers. Weights pre-packed to bf16
// hi/lo MFMA fragments in d_ws (b1 folded into spare MFMA k-slots).
// Round-8: bisection round. Exact r5 arithmetic (3-term FFN2, single acc
// chain, same op order) + r6's validated 4-way attention. ONLY new element:
// Mt is a compile-time template parameter (removes runtime tile guards from
// the unrolled FFN inner loop). r7's NaN bundle (acc-split + h-lo drop) is
// reverted pending bisection.

typedef __attribute__((ext_vector_type(8))) short short8;
typedef __attribute__((ext_vector_type(4))) float floatx4;
typedef __attribute__((ext_vector_type(4))) unsigned uint4v;

#define DEV static __device__ __forceinline__

namespace {
constexpr int D   = 8;
constexpr int T   = 60;
constexpr int DFF = 2048;
constexpr int SD  = 17;
constexpr int NT  = 512;             // 8 waves
constexpr int NW  = NT / 64;
constexpr int NBLK = DFF / 32;       // 64 blocks of 32 hidden cols
constexpr int BPW  = NBLK / NW;      // 8 blocks per wave
constexpr int LSTR = NBLK * 2048;    // shorts per layer in ws (256KB)
template <int N> struct IC { static constexpr int v = N; };
}

struct Params { const float* in[39]; float* out; };

// fp32 -> bf16 (round-half-up) — repack-time only
DEV unsigned short f2bf(float f) {
  unsigned u = __builtin_bit_cast(unsigned, f);
  return (unsigned short)((u + 0x8000u) >> 16);
}
DEV float bf2f(unsigned short h) {
  unsigned u = ((unsigned)h) << 16;
  return __builtin_bit_cast(float, u);
}
DEV floatx4 mfma16(short8 a, short8 b, floatx4 c) {
  return __builtin_amdgcn_mfma_f32_16x16x32_bf16(a, b, c, 0, 0, 0);
}
// packed fp32->bf16 (RTNE), 2 values -> 1 dword. No builtin on gfx950.
DEV unsigned cvtpk(float lo, float hi) {
  unsigned r;
  asm("v_cvt_pk_bf16_f32 %0, %1, %2" : "=v"(r) : "v"(lo), "v"(hi));
  return r;
}
DEV float lo2f(unsigned u) { return __builtin_bit_cast(float, u << 16); }
DEV float hi2f(unsigned u) { return __builtin_bit_cast(float, u & 0xffff0000u); }
DEV short8 pack4(unsigned a, unsigned b, unsigned c, unsigned d) {
  uint4v u = {a, b, c, d};
  return __builtin_bit_cast(short8, u);
}

// ---------------------------------------------------------------------------
// Repack kernel: per (layer L, 32-hidden block blk) write 2048 shorts:
//   [0:512) W1 A-frag tile 2*blk | [512:1024) tile 2*blk+1
//   [1024:1536) W2 A-frag hi     | [1536:2048) W2 A-frag lo
// W1 A-frag lane (gg,rr): gg0=hi(W1[j0+rr][0..7]) gg1=lo gg2=hi(dup)
//                         gg3={b1_hi,b1_lo,0..} (bias folded, B supplies 1.0)
// W2 A-frag lane (gg,rr), rr<8: W2[rr][jsel(gg,i)],
//   jsel(gg,i)= j0 + (i<4 ? gg*4+i : 16+gg*4+(i-4))  — matches the FFN1
//   output fragment order so FFN2's B-operand is lane-local.
// ---------------------------------------------------------------------------
__global__ __launch_bounds__(64) void repack_kernel(Params P, short* ws) {
  const int wg = blockIdx.x;              // 8 layers * 64 blocks
  const int L = wg >> 6, blk = wg & 63;
  const int l = (int)threadIdx.x, gg = l >> 4, rr = l & 15;
  const float *W1p, *b1p, *W2p;
  if (L < 6) { W1p = P.in[7] + L * 16384;  b1p = P.in[8] + L * 2048;  W2p = P.in[9] + L * 16384; }
  else { int m = L - 6; W1p = P.in[25] + m * 16384; b1p = P.in[26] + m * 2048; W2p = P.in[27] + m * 16384; }
  short* out = ws + (L * 64 + blk) * 2048;
  const int j0 = blk * 32;
  short8 z = {0,0,0,0,0,0,0,0};
  for (int tt = 0; tt < 2; ++tt) {
    int j = j0 + tt * 16 + rr;
    short8 r = z;
    if (gg == 3) {
      unsigned short h = f2bf(b1p[j]);
      r[0] = (short)h; r[1] = (short)f2bf(b1p[j] - bf2f(h));
    } else {
      const float* p = W1p + j * 8;
#pragma unroll
      for (int i = 0; i < 8; ++i) {
        float v = p[i];
        unsigned short h = f2bf(v);
        r[i] = (short)((gg == 1) ? f2bf(v - bf2f(h)) : h);
      }
    }
    *(short8*)(out + tt * 512 + l * 8) = r;
  }
  short8 wh = z, wl = z;
  if (rr < 8) {
#pragma unroll
    for (int i = 0; i < 8; ++i) {
      int j = j0 + (i < 4 ? gg * 4 + i : 16 + gg * 4 + (i - 4));
      float v = W2p[rr * 2048 + j];
      unsigned short h = f2bf(v);
      wh[i] = (short)h;
      wl[i] = (short)f2bf(v - bf2f(h));
    }
  }
  *(short8*)(out + 1024 + l * 8) = wh;
  *(short8*)(out + 1536 + l * 8) = wl;
}

// ---------------------------------------------------------------------------
__global__ __launch_bounds__(NT, 2) void tdec_kernel(Params P, const short* ws) {
  const int b    = blockIdx.x;
  const int tid  = (int)threadIdx.x;
  const int lane = tid & 63;
  const int wave = tid >> 6;
  const int gg   = lane >> 4;   // k-group within MFMA
  const int rr   = lane & 15;   // row/col within 16-tile

  __shared__ float buf[T][D];
  __shared__ __align__(16) float X[64][D];   // zero-padded rows >= R
  __shared__ float Mem[64][D];
  __shared__ float Qs[64][D];
  __shared__ float Ks[64][D];
  __shared__ float Vs[64][D];
  __shared__ float ATT[64][D];
  __shared__ __align__(16) float red[NW * 1024];  // FFN cross-wave partials 32KB
  __shared__ float wAll[10 * 288];
  __shared__ float lnp[40][D];
  __shared__ float b2all[8][D];
  __shared__ float fcw[SD][D];
  __shared__ float fcbv[SD];
  __shared__ float embw[D][SD];
  __shared__ float embbv[D];
  __shared__ float stv[SD];

  // ---------------- one-time staging of all small weights ----------------
  for (int o = tid; o < 2880; o += NT) {
    int a = o / 288, off = o - a * 288;
    const float *Wq, *Bq, *Wo, *Bo; int li;
    if (a < 6)              { li = a;            Wq=P.in[3];  Bq=P.in[4];  Wo=P.in[5];  Bo=P.in[6];  }
    else if (((a - 6) & 1) == 0) { li = (a-6)>>1; Wq=P.in[17]; Bq=P.in[18]; Wo=P.in[19]; Bo=P.in[20]; }
    else                    { li = (a-6)>>1;     Wq=P.in[21]; Bq=P.in[22]; Wo=P.in[23]; Bo=P.in[24]; }
    float v;
    if (off < 192)      v = Wq[li*192 + off];
    else if (off < 216) v = Bq[li*24  + off - 192];
    else if (off < 280) v = Wo[li*64  + off - 216];
    else                v = Bo[li*8   + off - 280];
    wAll[o] = v;
  }
  for (int o = tid; o < 320; o += NT) {
    int row = o >> 3, k = o & 7;
    const float* src;
    if (row < 24) { int li = row >> 2, w = row & 3;
      src = (w==0 ? P.in[11] : w==1 ? P.in[12] : w==2 ? P.in[13] : P.in[14]) + li*8;
    } else if (row < 26) src = (row == 24 ? P.in[15] : P.in[16]);
    else if (row < 38) { int q = row - 26, li = q / 6, w = q - li*6;
      src = (w==0?P.in[29]:w==1?P.in[30]:w==2?P.in[31]:w==3?P.in[32]:w==4?P.in[33]:P.in[34]) + li*8;
    } else src = (row == 38 ? P.in[35] : P.in[36]);
    lnp[row][k] = src[k];
  }
  if (tid < 64) { int row = tid >> 3, k = tid & 7;
    b2all[row][k] = (row < 6) ? P.in[10][row*8 + k] : P.in[28][(row-6)*8 + k]; }
  if (tid < 136) fcw[tid >> 3][tid & 7] = P.in[37][tid];
  if (tid < SD)  fcbv[tid] = P.in[38][tid];
  if (tid < 136) embw[tid / 17][tid % 17] = P.in[1][tid];
  if (tid < D)   embbv[tid] = P.in[2][tid];
  if (tid < D)   buf[0][tid] = P.in[0][b*D + tid];
  __syncthreads();

  const short8 zero8 = {0,0,0,0,0,0,0,0};
  const floatx4 zf4  = {0.f,0.f,0.f,0.f};

  // ---------------- helpers ----------------
  auto proj8 = [&](float (*dst)[D], const float (*src)[D], const float* w,
                   const float* bias, int R) {
    for (int o = tid; o < (R << 3); o += NT) {
      int r = o >> 3, d = o & 7;
      const float* wr = w + d * 8;
      const float* xr = src[r];
      float s = bias[d];
#pragma unroll
      for (int k = 0; k < 8; ++k) s += xr[k] * wr[k];
      dst[r][d] = s;
    }
  };

  // fixed-shift single-pass softmax (LN-bounded scores; exp(s-10) safe).
  // 4 threads per (p,h) when R<=32, else 2; shfl_xor combine.
  auto attn = [&](int R, bool causal) {
    if (R <= 32) {
      int p = tid >> 4, h2 = ((tid >> 2) & 3) << 1, e = tid & 3;
      if (p < R) {
        float q0 = Qs[p][h2]     * 0.70710678118654752f;
        float q1 = Qs[p][h2 + 1] * 0.70710678118654752f;
        int lim = causal ? p : (R - 1);
        float l = 0.f, a0 = 0.f, a1 = 0.f;
        for (int j = e; j <= lim; j += 4) {
          float s = q0 * Ks[j][h2] + q1 * Ks[j][h2 + 1] - 10.f;
          float ev = __expf(s);
          l += ev; a0 += ev * Vs[j][h2]; a1 += ev * Vs[j][h2 + 1];
        }
        l  += __shfl_xor(l, 1);  l  += __shfl_xor(l, 2);
        a0 += __shfl_xor(a0, 1); a0 += __shfl_xor(a0, 2);
        a1 += __shfl_xor(a1, 1); a1 += __shfl_xor(a1, 2);
        if (e == 0) {
          float rl = 1.f / l;
          ATT[p][h2] = a0 * rl; ATT[p][h2 + 1] = a1 * rl;
        }
      }
    } else {
      int p = tid >> 3, h2 = ((tid >> 1) & 3) << 1, e = tid & 1;
      if (p < R) {
        float q0 = Qs[p][h2]     * 0.70710678118654752f;
        float q1 = Qs[p][h2 + 1] * 0.70710678118654752f;
        int lim = causal ? p : (R - 1);
        float l = 0.f, a0 = 0.f, a1 = 0.f;
        for (int j = e; j <= lim; j += 2) {
          float s = q0 * Ks[j][h2] + q1 * Ks[j][h2 + 1] - 10.f;
          float ev = __expf(s);
          l += ev; a0 += ev * Vs[j][h2]; a1 += ev * Vs[j][h2 + 1];
        }
        l  += __shfl_xor(l, 1);
        a0 += __shfl_xor(a0, 1);
        a1 += __shfl_xor(a1, 1);
        if (e == 0) {
          float rl = 1.f / l;
          ATT[p][h2] = a0 * rl; ATT[p][h2 + 1] = a1 * rl;
        }
      }
    }
  };

  auto oproj_ln = [&](const float* wo, const float* bo, const float* g,
                      const float* bb, int R) {
    if (tid < R) {
      float o[8];
#pragma unroll
      for (int d = 0; d < 8; ++d) {
        float s = bo[d] + X[tid][d];
#pragma unroll
        for (int k = 0; k < 8; ++k) s += ATT[tid][k] * wo[d * 8 + k];
        o[d] = s;
      }
      float m = 0.f;
#pragma unroll
      for (int k = 0; k < 8; ++k) m += o[k];
      m *= 0.125f;
      float v = 0.f;
#pragma unroll
      for (int k = 0; k < 8; ++k) { float dm = o[k] - m; v += dm * dm; }
      float rs = rsqrtf(v * 0.125f + 1e-5f);
#pragma unroll
      for (int k = 0; k < 8; ++k) X[tid][k] = (o[k] - m) * rs * g[k] + bb[k];
    }
  };

  auto ln_rows = [&](float (*dst)[D], const float (*src)[D], const float* g,
                     const float* bb, int R) {
    if (tid < R) {
      float o[8];
#pragma unroll
      for (int k = 0; k < 8; ++k) o[k] = src[tid][k];
      float m = 0.f;
#pragma unroll
      for (int k = 0; k < 8; ++k) m += o[k];
      m *= 0.125f;
      float v = 0.f;
#pragma unroll
      for (int k = 0; k < 8; ++k) { float dm = o[k] - m; v += dm * dm; }
      float rs = rsqrtf(v * 0.125f + 1e-5f);
#pragma unroll
      for (int k = 0; k < 8; ++k) dst[tid][k] = (o[k] - m) * rs * g[k] + bb[k];
    }
  };

  auto mha = [&](int a, float (*kvsrc)[D], bool causal, int R,
                 const float* g, const float* bb) {
    const float* wq = &wAll[a * 288];
    proj8(Qs, X,     wq +   0, wq + 192, R);
    proj8(Ks, kvsrc, wq +  64, wq + 200, R);
    proj8(Vs, kvsrc, wq + 128, wq + 208, R);
    __syncthreads();
    attn(R, causal);
    __syncthreads();
    oproj_ln(wq + 216, wq + 280, g, bb, R);
    __syncthreads();
  };

  // FFN, swapped-operand form, arithmetic IDENTICAL to round-5 (3 MFMA
  // terms, single accumulator chain, same order); MT is compile-time.
  auto ffn = [&](auto MTC, const short* wsL, const float* b2, const float* g,
                 const float* bb, int R) {
    constexpr int MT = decltype(MTC)::v;
    // issue block-0 fragment loads first; bx-setup VALU hides the latency
    const short* pb = wsL + (wave * BPW) * 2048;
    short8 a0  = *(const short8*)(pb + lane * 8);
    short8 a1  = *(const short8*)(pb + 512 + lane * 8);
    short8 w2h = *(const short8*)(pb + 1024 + lane * 8);
    short8 w2l = *(const short8*)(pb + 1536 + lane * 8);

    // B-frags (X^T) per r-tile; lane variant: gg0/1=x_hi, gg2=x_lo, gg3=ones
    short8 bx[MT];
#pragma unroll
    for (int mt = 0; mt < MT; ++mt) {
      short8 v;
      if (gg == 3) {
        v = zero8;
        v[0] = (short)0x3F80; v[1] = (short)0x3F80;
      } else {
        int r = mt * 16 + rr;
        float4 A = *(const float4*)&X[r][0];
        float4 Bv = *(const float4*)&X[r][4];
        unsigned u0 = cvtpk(A.x, A.y), u1 = cvtpk(A.z, A.w);
        unsigned u2 = cvtpk(Bv.x, Bv.y), u3 = cvtpk(Bv.z, Bv.w);
        if (gg == 2) {
          unsigned l0 = cvtpk(A.x - lo2f(u0), A.y - hi2f(u0));
          unsigned l1 = cvtpk(A.z - lo2f(u1), A.w - hi2f(u1));
          unsigned l2 = cvtpk(Bv.x - lo2f(u2), Bv.y - hi2f(u2));
          unsigned l3 = cvtpk(Bv.z - lo2f(u3), Bv.w - hi2f(u3));
          v = pack4(l0, l1, l2, l3);
        } else {
          v = pack4(u0, u1, u2, u3);
        }
      }
      bx[mt] = v;
    }

    floatx4 acc[MT];
#pragma unroll
    for (int mt = 0; mt < MT; ++mt) acc[mt] = zf4;

    for (int blkI = 0; blkI < BPW; ++blkI) {
      short8 na0 = zero8, na1 = zero8, nw2h = zero8, nw2l = zero8;
      if (blkI + 1 < BPW) {            // prefetch next block's fragments
        const short* pn = pb + (blkI + 1) * 2048;
        na0  = *(const short8*)(pn + lane * 8);
        na1  = *(const short8*)(pn + 512 + lane * 8);
        nw2h = *(const short8*)(pn + 1024 + lane * 8);
        nw2l = *(const short8*)(pn + 1536 + lane * 8);
      }
#pragma unroll
      for (int mt = 0; mt < MT; ++mt) {
        floatx4 h0 = mfma16(a0, bx[mt], zf4);   // rows j0..j0+15, cols=pos
        floatx4 h1 = mfma16(a1, bx[mt], zf4);   // rows j0+16..j0+31
        float v0 = fmaxf(h0[0], 0.f), v1 = fmaxf(h0[1], 0.f);
        float v2 = fmaxf(h0[2], 0.f), v3 = fmaxf(h0[3], 0.f);
        float v4 = fmaxf(h1[0], 0.f), v5 = fmaxf(h1[1], 0.f);
        float v6 = fmaxf(h1[2], 0.f), v7 = fmaxf(h1[3], 0.f);
        unsigned u0 = cvtpk(v0, v1), u1 = cvtpk(v2, v3);
        unsigned u2 = cvtpk(v4, v5), u3 = cvtpk(v6, v7);
        unsigned l0 = cvtpk(v0 - lo2f(u0), v1 - hi2f(u0));
        unsigned l1 = cvtpk(v2 - lo2f(u1), v3 - hi2f(u1));
        unsigned l2 = cvtpk(v4 - lo2f(u2), v5 - hi2f(u2));
        unsigned l3 = cvtpk(v6 - lo2f(u3), v7 - hi2f(u3));
        short8 ah = pack4(u0, u1, u2, u3);
        short8 al = pack4(l0, l1, l2, l3);
        // A-operand = W2 (rows = d), B-operand = h (cols = pos):
        // D[row=d][col=pos] matches the reduce below.
        acc[mt] = mfma16(w2h, ah, acc[mt]);
        acc[mt] = mfma16(w2h, al, acc[mt]);
        acc[mt] = mfma16(w2l, ah, acc[mt]);
      }
      a0 = na0; a1 = na1; w2h = nw2h; w2l = nw2l;
    }

    // cross-wave reduce + residual + bias + LN, fused per row
#pragma unroll
    for (int mt = 0; mt < MT; ++mt)
      *(floatx4*)&red[(((wave << 2) + mt) << 8) + (lane << 2)] = acc[mt];
    __syncthreads();
    if (tid < R) {
      int r = tid, mt = r >> 4, rl = r & 15;
      float o[8];
#pragma unroll
      for (int d = 0; d < 8; ++d) {
        float s = X[r][d] + b2[d];
        // acc layout: lane (gg=d>>2, rr=rl) reg (d&3) holds out^T[d][mt*16+rl]
        int base = (mt << 8) + ((((d >> 2) << 4) + rl) << 2) + (d & 3);
#pragma unroll
        for (int w = 0; w < NW; ++w) s += red[(w << 10) + base];
        o[d] = s;
      }
      float m = 0.f;
#pragma unroll
      for (int k = 0; k < 8; ++k) m += o[k];
      m *= 0.125f;
      float var = 0.f;
#pragma unroll
      for (int k = 0; k < 8; ++k) { float dm = o[k] - m; var += dm * dm; }
      float rs = rsqrtf(var * 0.125f + 1e-5f);
#pragma unroll
      for (int k = 0; k < 8; ++k) X[r][k] = (o[k] - m) * rs * g[k] + bb[k];
    }
    __syncthreads();
  };

  auto ffn_d = [&](const short* wsL, const float* b2, const float* g,
                   const float* bb, int R, int Mt) {
    switch (Mt) {
      case 1: ffn(IC<1>{}, wsL, b2, g, bb, R); break;
      case 2: ffn(IC<2>{}, wsL, b2, g, bb, R); break;
      case 3: ffn(IC<3>{}, wsL, b2, g, bb, R); break;
      default: ffn(IC<4>{}, wsL, b2, g, bb, R); break;
    }
  };

  // ---------------- the 60-step scan ----------------
  for (int t = 0; t < T; ++t) {
    const int R = t + 1;
    const int Mt = (R + 15) >> 4;

    for (int o = tid; o < 512; o += NT) {
      int r = o >> 3, d = o & 7;
      X[r][d] = (r < R) ? buf[r][d] : 0.f;
    }
    __syncthreads();

    // encoder: 6 layers, keys <= t
    for (int li = 0; li < 6; ++li) {
      mha(li, X, false, R, lnp[li * 4 + 0], lnp[li * 4 + 1]);
      ffn_d(ws + li * LSTR, b2all[li], lnp[li * 4 + 2], lnp[li * 4 + 3], R, Mt);
    }
    ln_rows(X, X, lnp[24], lnp[25], R);
    __syncthreads();
    for (int o = tid; o < 512; o += NT) {
      int r = o >> 3, d = o & 7;
      if (r < R) Mem[r][d] = X[r][d];
      X[r][d] = (r < R) ? buf[r][d] : 0.f;
    }
    __syncthreads();

    // decoder: 2 layers (causal self, cross vs Mem, FFN)
    for (int li = 0; li < 2; ++li) {
      mha(6 + li * 2, X,   true,  R, lnp[26 + li * 6 + 0], lnp[26 + li * 6 + 1]);
      mha(7 + li * 2, Mem, false, R, lnp[26 + li * 6 + 2], lnp[26 + li * 6 + 3]);
      ffn_d(ws + (6 + li) * LSTR, b2all[6 + li],
            lnp[26 + li * 6 + 4], lnp[26 + li * 6 + 5], R, Mt);
    }
    ln_rows(X, X, lnp[38], lnp[39], R);
    __syncthreads();

    // st = y[t] @ fc_W^T + fc_b  -> output; then embed back into buf[t+1]
    if (tid < SD) {
      float s = fcbv[tid];
#pragma unroll
      for (int k = 0; k < 8; ++k) s += X[t][k] * fcw[tid][k];
      stv[tid] = s;
      P.out[(b * T + t) * SD + tid] = s;
    }
    __syncthreads();
    if (t + 1 < T && tid < D) {
      float s = embbv[tid];
#pragma unroll
      for (int k = 0; k < SD; ++k) s += stv[k] * embw[tid][k];
      buf[t + 1][tid] = s;
    }
    __syncthreads();
  }
}

extern "C" void kernel_launch(void* const* d_in, const int* in_sizes, int n_in,
                              void* d_out, int out_size, void* d_ws, size_t ws_size,
                              hipStream_t stream) {
  (void)in_sizes; (void)n_in; (void)ws_size; (void)out_size;
  Params P;
  for (int i = 0; i < 39; ++i) P.in[i] = (const float*)d_in[i];
  P.out = (float*)d_out;
  short* ws = (short*)d_ws;   // 8 layers * 256KB = 2MB of packed fragments
  repack_kernel<<<dim3(8 * NBLK), dim3(64), 0, stream>>>(P, ws);
  tdec_kernel<<<dim3(128), dim3(NT), 0, stream>>>(P, ws);
}

// Round 10
// 3473.229 us; speedup vs baseline: 1.2419x; 1.2419x over previous
//
#include <hip/hip_runtime.h>

// TransformerDecoder scan: B=128 independent sequences, one workgroup each,
// 8 waves/WG. FFN is swapped-operand MFMA (h^T = W1·X^T) so the 2048-wide
// hidden activation stays entirely in registers. Weights pre-packed to bf16
// hi/lo MFMA fragments in d_ws (b1 folded into spare MFMA k-slots).
// Round-10: r5 base (3-term FFN2 hi/lo — FROZEN: r9 proved the h-lo term is
// load-bearing, scan amplifies ~x800) + 4-way attention (validated r6/r8)
// + NEW: last decoder layer computes ONLY row t (its other rows are never
// consumed): K/V proj full, Q/attn/oproj/FFN/final-LN single-row.

typedef __attribute__((ext_vector_type(8))) short short8;
typedef __attribute__((ext_vector_type(4))) float floatx4;
typedef __attribute__((ext_vector_type(4))) unsigned uint4v;

#define DEV static __device__ __forceinline__

namespace {
constexpr int D   = 8;
constexpr int T   = 60;
constexpr int DFF = 2048;
constexpr int SD  = 17;
constexpr int NT  = 512;             // 8 waves
constexpr int NW  = NT / 64;
constexpr int NBLK = DFF / 32;       // 64 blocks of 32 hidden cols
constexpr int BPW  = NBLK / NW;      // 8 blocks per wave
constexpr int LSTR = NBLK * 2048;    // shorts per layer in ws (256KB)
}

struct Params { const float* in[39]; float* out; };

// fp32 -> bf16 (round-half-up) — repack-time only
DEV unsigned short f2bf(float f) {
  unsigned u = __builtin_bit_cast(unsigned, f);
  return (unsigned short)((u + 0x8000u) >> 16);
}
DEV float bf2f(unsigned short h) {
  unsigned u = ((unsigned)h) << 16;
  return __builtin_bit_cast(float, u);
}
DEV floatx4 mfma16(short8 a, short8 b, floatx4 c) {
  return __builtin_amdgcn_mfma_f32_16x16x32_bf16(a, b, c, 0, 0, 0);
}
// packed fp32->bf16 (RTNE), 2 values -> 1 dword. No builtin on gfx950.
DEV unsigned cvtpk(float lo, float hi) {
  unsigned r;
  asm("v_cvt_pk_bf16_f32 %0, %1, %2" : "=v"(r) : "v"(lo), "v"(hi));
  return r;
}
DEV float lo2f(unsigned u) { return __builtin_bit_cast(float, u << 16); }
DEV float hi2f(unsigned u) { return __builtin_bit_cast(float, u & 0xffff0000u); }
DEV short8 pack4(unsigned a, unsigned b, unsigned c, unsigned d) {
  uint4v u = {a, b, c, d};
  return __builtin_bit_cast(short8, u);
}

// ---------------------------------------------------------------------------
// Repack kernel: per (layer L, 32-hidden block blk) write 2048 shorts:
//   [0:512) W1 A-frag tile 2*blk | [512:1024) tile 2*blk+1
//   [1024:1536) W2 A-frag hi     | [1536:2048) W2 A-frag lo
// W1 A-frag lane (gg,rr): gg0=hi(W1[j0+rr][0..7]) gg1=lo gg2=hi(dup)
//                         gg3={b1_hi,b1_lo,0..} (bias folded, B supplies 1.0)
// W2 A-frag lane (gg,rr), rr<8: W2[rr][jsel(gg,i)],
//   jsel(gg,i)= j0 + (i<4 ? gg*4+i : 16+gg*4+(i-4))  — matches the FFN1
//   output fragment order so FFN2's B-operand is lane-local.
// ---------------------------------------------------------------------------
__global__ __launch_bounds__(64) void repack_kernel(Params P, short* ws) {
  const int wg = blockIdx.x;              // 8 layers * 64 blocks
  const int L = wg >> 6, blk = wg & 63;
  const int l = (int)threadIdx.x, gg = l >> 4, rr = l & 15;
  const float *W1p, *b1p, *W2p;
  if (L < 6) { W1p = P.in[7] + L * 16384;  b1p = P.in[8] + L * 2048;  W2p = P.in[9] + L * 16384; }
  else { int m = L - 6; W1p = P.in[25] + m * 16384; b1p = P.in[26] + m * 2048; W2p = P.in[27] + m * 16384; }
  short* out = ws + (L * 64 + blk) * 2048;
  const int j0 = blk * 32;
  short8 z = {0,0,0,0,0,0,0,0};
  for (int tt = 0; tt < 2; ++tt) {
    int j = j0 + tt * 16 + rr;
    short8 r = z;
    if (gg == 3) {
      unsigned short h = f2bf(b1p[j]);
      r[0] = (short)h; r[1] = (short)f2bf(b1p[j] - bf2f(h));
    } else {
      const float* p = W1p + j * 8;
#pragma unroll
      for (int i = 0; i < 8; ++i) {
        float v = p[i];
        unsigned short h = f2bf(v);
        r[i] = (short)((gg == 1) ? f2bf(v - bf2f(h)) : h);
      }
    }
    *(short8*)(out + tt * 512 + l * 8) = r;
  }
  short8 wh = z, wl = z;
  if (rr < 8) {
#pragma unroll
    for (int i = 0; i < 8; ++i) {
      int j = j0 + (i < 4 ? gg * 4 + i : 16 + gg * 4 + (i - 4));
      float v = W2p[rr * 2048 + j];
      unsigned short h = f2bf(v);
      wh[i] = (short)h;
      wl[i] = (short)f2bf(v - bf2f(h));
    }
  }
  *(short8*)(out + 1024 + l * 8) = wh;
  *(short8*)(out + 1536 + l * 8) = wl;
}

// ---------------------------------------------------------------------------
__global__ __launch_bounds__(NT, 2) void tdec_kernel(Params P, const short* ws) {
  const int b    = blockIdx.x;
  const int tid  = (int)threadIdx.x;
  const int lane = tid & 63;
  const int wave = tid >> 6;
  const int gg   = lane >> 4;   // k-group within MFMA
  const int rr   = lane & 15;   // row/col within 16-tile

  __shared__ float buf[T][D];
  __shared__ __align__(16) float X[64][D];   // zero-padded rows >= R
  __shared__ float Mem[64][D];
  __shared__ float Qs[64][D];
  __shared__ float Ks[64][D];
  __shared__ float Vs[64][D];
  __shared__ float ATT[64][D];
  __shared__ __align__(16) float red[NW * 1024];  // FFN cross-wave partials 32KB
  __shared__ float wAll[10 * 288];
  __shared__ float lnp[40][D];
  __shared__ float b2all[8][D];
  __shared__ float fcw[SD][D];
  __shared__ float fcbv[SD];
  __shared__ float embw[D][SD];
  __shared__ float embbv[D];
  __shared__ float stv[SD];

  // ---------------- one-time staging of all small weights ----------------
  for (int o = tid; o < 2880; o += NT) {
    int a = o / 288, off = o - a * 288;
    const float *Wq, *Bq, *Wo, *Bo; int li;
    if (a < 6)              { li = a;            Wq=P.in[3];  Bq=P.in[4];  Wo=P.in[5];  Bo=P.in[6];  }
    else if (((a - 6) & 1) == 0) { li = (a-6)>>1; Wq=P.in[17]; Bq=P.in[18]; Wo=P.in[19]; Bo=P.in[20]; }
    else                    { li = (a-6)>>1;     Wq=P.in[21]; Bq=P.in[22]; Wo=P.in[23]; Bo=P.in[24]; }
    float v;
    if (off < 192)      v = Wq[li*192 + off];
    else if (off < 216) v = Bq[li*24  + off - 192];
    else if (off < 280) v = Wo[li*64  + off - 216];
    else                v = Bo[li*8   + off - 280];
    wAll[o] = v;
  }
  for (int o = tid; o < 320; o += NT) {
    int row = o >> 3, k = o & 7;
    const float* src;
    if (row < 24) { int li = row >> 2, w = row & 3;
      src = (w==0 ? P.in[11] : w==1 ? P.in[12] : w==2 ? P.in[13] : P.in[14]) + li*8;
    } else if (row < 26) src = (row == 24 ? P.in[15] : P.in[16]);
    else if (row < 38) { int q = row - 26, li = q / 6, w = q - li*6;
      src = (w==0?P.in[29]:w==1?P.in[30]:w==2?P.in[31]:w==3?P.in[32]:w==4?P.in[33]:P.in[34]) + li*8;
    } else src = (row == 38 ? P.in[35] : P.in[36]);
    lnp[row][k] = src[k];
  }
  if (tid < 64) { int row = tid >> 3, k = tid & 7;
    b2all[row][k] = (row < 6) ? P.in[10][row*8 + k] : P.in[28][(row-6)*8 + k]; }
  if (tid < 136) fcw[tid >> 3][tid & 7] = P.in[37][tid];
  if (tid < SD)  fcbv[tid] = P.in[38][tid];
  if (tid < 136) embw[tid / 17][tid % 17] = P.in[1][tid];
  if (tid < D)   embbv[tid] = P.in[2][tid];
  if (tid < D)   buf[0][tid] = P.in[0][b*D + tid];
  __syncthreads();

  const short8 zero8 = {0,0,0,0,0,0,0,0};
  const floatx4 zf4  = {0.f,0.f,0.f,0.f};

  // ---------------- helpers ----------------
  auto proj8 = [&](float (*dst)[D], const float (*src)[D], const float* w,
                   const float* bias, int R) {
    for (int o = tid; o < (R << 3); o += NT) {
      int r = o >> 3, d = o & 7;
      const float* wr = w + d * 8;
      const float* xr = src[r];
      float s = bias[d];
#pragma unroll
      for (int k = 0; k < 8; ++k) s += xr[k] * wr[k];
      dst[r][d] = s;
    }
  };

  // fixed-shift single-pass softmax (LN-bounded scores; exp(s-10) safe).
  // 4 threads per (p,h) when R<=32, else 2; shfl_xor combine.
  auto attn = [&](int R, bool causal) {
    if (R <= 32) {
      int p = tid >> 4, h2 = ((tid >> 2) & 3) << 1, e = tid & 3;
      if (p < R) {
        float q0 = Qs[p][h2]     * 0.70710678118654752f;
        float q1 = Qs[p][h2 + 1] * 0.70710678118654752f;
        int lim = causal ? p : (R - 1);
        float l = 0.f, a0 = 0.f, a1 = 0.f;
        for (int j = e; j <= lim; j += 4) {
          float s = q0 * Ks[j][h2] + q1 * Ks[j][h2 + 1] - 10.f;
          float ev = __expf(s);
          l += ev; a0 += ev * Vs[j][h2]; a1 += ev * Vs[j][h2 + 1];
        }
        l  += __shfl_xor(l, 1);  l  += __shfl_xor(l, 2);
        a0 += __shfl_xor(a0, 1); a0 += __shfl_xor(a0, 2);
        a1 += __shfl_xor(a1, 1); a1 += __shfl_xor(a1, 2);
        if (e == 0) {
          float rl = 1.f / l;
          ATT[p][h2] = a0 * rl; ATT[p][h2 + 1] = a1 * rl;
        }
      }
    } else {
      int p = tid >> 3, h2 = ((tid >> 1) & 3) << 1, e = tid & 1;
      if (p < R) {
        float q0 = Qs[p][h2]     * 0.70710678118654752f;
        float q1 = Qs[p][h2 + 1] * 0.70710678118654752f;
        int lim = causal ? p : (R - 1);
        float l = 0.f, a0 = 0.f, a1 = 0.f;
        for (int j = e; j <= lim; j += 2) {
          float s = q0 * Ks[j][h2] + q1 * Ks[j][h2 + 1] - 10.f;
          float ev = __expf(s);
          l += ev; a0 += ev * Vs[j][h2]; a1 += ev * Vs[j][h2 + 1];
        }
        l  += __shfl_xor(l, 1);
        a0 += __shfl_xor(a0, 1);
        a1 += __shfl_xor(a1, 1);
        if (e == 0) {
          float rl = 1.f / l;
          ATT[p][h2] = a0 * rl; ATT[p][h2 + 1] = a1 * rl;
        }
      }
    }
  };

  auto oproj_ln = [&](const float* wo, const float* bo, const float* g,
                      const float* bb, int R) {
    if (tid < R) {
      float o[8];
#pragma unroll
      for (int d = 0; d < 8; ++d) {
        float s = bo[d] + X[tid][d];
#pragma unroll
        for (int k = 0; k < 8; ++k) s += ATT[tid][k] * wo[d * 8 + k];
        o[d] = s;
      }
      float m = 0.f;
#pragma unroll
      for (int k = 0; k < 8; ++k) m += o[k];
      m *= 0.125f;
      float v = 0.f;
#pragma unroll
      for (int k = 0; k < 8; ++k) { float dm = o[k] - m; v += dm * dm; }
      float rs = rsqrtf(v * 0.125f + 1e-5f);
#pragma unroll
      for (int k = 0; k < 8; ++k) X[tid][k] = (o[k] - m) * rs * g[k] + bb[k];
    }
  };

  auto ln_rows = [&](float (*dst)[D], const float (*src)[D], const float* g,
                     const float* bb, int R) {
    if (tid < R) {
      float o[8];
#pragma unroll
      for (int k = 0; k < 8; ++k) o[k] = src[tid][k];
      float m = 0.f;
#pragma unroll
      for (int k = 0; k < 8; ++k) m += o[k];
      m *= 0.125f;
      float v = 0.f;
#pragma unroll
      for (int k = 0; k < 8; ++k) { float dm = o[k] - m; v += dm * dm; }
      float rs = rsqrtf(v * 0.125f + 1e-5f);
#pragma unroll
      for (int k = 0; k < 8; ++k) dst[tid][k] = (o[k] - m) * rs * g[k] + bb[k];
    }
  };

  auto mha = [&](int a, float (*kvsrc)[D], bool causal, int R,
                 const float* g, const float* bb) {
    const float* wq = &wAll[a * 288];
    proj8(Qs, X,     wq +   0, wq + 192, R);
    proj8(Ks, kvsrc, wq +  64, wq + 200, R);
    proj8(Vs, kvsrc, wq + 128, wq + 208, R);
    __syncthreads();
    attn(R, causal);
    __syncthreads();
    oproj_ln(wq + 216, wq + 280, g, bb, R);
    __syncthreads();
  };

  // MHA computing ONLY row t of the output (K/V proj still full R rows).
  // For row t both causal and keymask reduce to "attend j in [0,R)".
  auto mha_row = [&](int a, float (*kvsrc)[D], int R, int t,
                     const float* g, const float* bb) {
    const float* wq = &wAll[a * 288];
    proj8(Ks, kvsrc, wq +  64, wq + 200, R);
    proj8(Vs, kvsrc, wq + 128, wq + 208, R);
    if (tid < 8) {                      // Q projection, row t only
      int d = tid;
      const float* wr = wq + d * 8;
      float s = wq[192 + d];
#pragma unroll
      for (int k = 0; k < 8; ++k) s += X[t][k] * wr[k];
      Qs[t][d] = s;
    }
    __syncthreads();
    if (tid < 32) {                     // attention row t: 8-way j-split
      int h2 = (tid >> 3) << 1, e = tid & 7;
      float q0 = Qs[t][h2]     * 0.70710678118654752f;
      float q1 = Qs[t][h2 + 1] * 0.70710678118654752f;
      float l = 0.f, a0 = 0.f, a1 = 0.f;
      for (int j = e; j < R; j += 8) {
        float s = q0 * Ks[j][h2] + q1 * Ks[j][h2 + 1] - 10.f;
        float ev = __expf(s);
        l += ev; a0 += ev * Vs[j][h2]; a1 += ev * Vs[j][h2 + 1];
      }
      l  += __shfl_xor(l, 1);  l  += __shfl_xor(l, 2);  l  += __shfl_xor(l, 4);
      a0 += __shfl_xor(a0, 1); a0 += __shfl_xor(a0, 2); a0 += __shfl_xor(a0, 4);
      a1 += __shfl_xor(a1, 1); a1 += __shfl_xor(a1, 2); a1 += __shfl_xor(a1, 4);
      if (e == 0) {
        float rl = 1.f / l;
        ATT[t][h2] = a0 * rl; ATT[t][h2 + 1] = a1 * rl;
      }
    }
    __syncthreads();
    if (tid == 0) {                     // oproj + residual + LN, row t
      float o[8];
#pragma unroll
      for (int d = 0; d < 8; ++d) {
        float s = wq[280 + d] + X[t][d];
#pragma unroll
        for (int k = 0; k < 8; ++k) s += ATT[t][k] * wq[216 + d * 8 + k];
        o[d] = s;
      }
      float m = 0.f;
#pragma unroll
      for (int k = 0; k < 8; ++k) m += o[k];
      m *= 0.125f;
      float v = 0.f;
#pragma unroll
      for (int k = 0; k < 8; ++k) { float dm = o[k] - m; v += dm * dm; }
      float rs = rsqrtf(v * 0.125f + 1e-5f);
#pragma unroll
      for (int k = 0; k < 8; ++k) X[t][k] = (o[k] - m) * rs * g[k] + bb[k];
    }
    __syncthreads();
  };

  // FFN, swapped-operand form (r5 3-term arithmetic — FROZEN).
  auto ffn = [&](const short* wsL, const float* b2, const float* g,
                 const float* bb, int R, int Mt) {
    // issue block-0 fragment loads first; bx-setup VALU hides the latency
    const short* pb = wsL + (wave * BPW) * 2048;
    short8 a0  = *(const short8*)(pb + lane * 8);
    short8 a1  = *(const short8*)(pb + 512 + lane * 8);
    short8 w2h = *(const short8*)(pb + 1024 + lane * 8);
    short8 w2l = *(const short8*)(pb + 1536 + lane * 8);

    // B-frags (X^T) per r-tile; lane variant: gg0/1=x_hi, gg2=x_lo, gg3=ones
    short8 bx[4];
#pragma unroll
    for (int mt = 0; mt < 4; ++mt) {
      short8 v = zero8;
      if (mt < Mt) {
        if (gg == 3) { v[0] = (short)0x3F80; v[1] = (short)0x3F80; }
        else {
          int r = mt * 16 + rr;
          float4 A = *(const float4*)&X[r][0];
          float4 Bv = *(const float4*)&X[r][4];
          unsigned u0 = cvtpk(A.x, A.y), u1 = cvtpk(A.z, A.w);
          unsigned u2 = cvtpk(Bv.x, Bv.y), u3 = cvtpk(Bv.z, Bv.w);
          if (gg == 2) {
            unsigned l0 = cvtpk(A.x - lo2f(u0), A.y - hi2f(u0));
            unsigned l1 = cvtpk(A.z - lo2f(u1), A.w - hi2f(u1));
            unsigned l2 = cvtpk(Bv.x - lo2f(u2), Bv.y - hi2f(u2));
            unsigned l3 = cvtpk(Bv.z - lo2f(u3), Bv.w - hi2f(u3));
            v = pack4(l0, l1, l2, l3);
          } else {
            v = pack4(u0, u1, u2, u3);
          }
        }
      }
      bx[mt] = v;
    }

    floatx4 acc[4] = {zf4, zf4, zf4, zf4};
    for (int blkI = 0; blkI < BPW; ++blkI) {
      short8 na0 = zero8, na1 = zero8, nw2h = zero8, nw2l = zero8;
      if (blkI + 1 < BPW) {            // prefetch next block's fragments
        const short* pn = pb + (blkI + 1) * 2048;
        na0  = *(const short8*)(pn + lane * 8);
        na1  = *(const short8*)(pn + 512 + lane * 8);
        nw2h = *(const short8*)(pn + 1024 + lane * 8);
        nw2l = *(const short8*)(pn + 1536 + lane * 8);
      }
#pragma unroll
      for (int mt = 0; mt < 4; ++mt) {
        if (mt < Mt) {
          floatx4 h0 = mfma16(a0, bx[mt], zf4);   // rows j0..j0+15, cols=pos
          floatx4 h1 = mfma16(a1, bx[mt], zf4);   // rows j0+16..j0+31
          float v0 = fmaxf(h0[0], 0.f), v1 = fmaxf(h0[1], 0.f);
          float v2 = fmaxf(h0[2], 0.f), v3 = fmaxf(h0[3], 0.f);
          float v4 = fmaxf(h1[0], 0.f), v5 = fmaxf(h1[1], 0.f);
          float v6 = fmaxf(h1[2], 0.f), v7 = fmaxf(h1[3], 0.f);
          unsigned u0 = cvtpk(v0, v1), u1 = cvtpk(v2, v3);
          unsigned u2 = cvtpk(v4, v5), u3 = cvtpk(v6, v7);
          unsigned l0 = cvtpk(v0 - lo2f(u0), v1 - hi2f(u0));
          unsigned l1 = cvtpk(v2 - lo2f(u1), v3 - hi2f(u1));
          unsigned l2 = cvtpk(v4 - lo2f(u2), v5 - hi2f(u2));
          unsigned l3 = cvtpk(v6 - lo2f(u3), v7 - hi2f(u3));
          short8 ah = pack4(u0, u1, u2, u3);
          short8 al = pack4(l0, l1, l2, l3);
          // A-operand = W2 (rows = d), B-operand = h (cols = pos):
          // D[row=d][col=pos] matches the reduce below.
          acc[mt] = mfma16(w2h, ah, acc[mt]);
          acc[mt] = mfma16(w2h, al, acc[mt]);
          acc[mt] = mfma16(w2l, ah, acc[mt]);
        }
      }
      a0 = na0; a1 = na1; w2h = nw2h; w2l = nw2l;
    }

    // cross-wave reduce + residual + bias + LN, fused per row
#pragma unroll
    for (int mt = 0; mt < 4; ++mt)
      if (mt < Mt)
        *(floatx4*)&red[(((wave << 2) + mt) << 8) + (lane << 2)] = acc[mt];
    __syncthreads();
    if (tid < R) {
      int r = tid, mt = r >> 4, rl = r & 15;
      float o[8];
#pragma unroll
      for (int d = 0; d < 8; ++d) {
        float s = X[r][d] + b2[d];
        // acc layout: lane (gg=d>>2, rr=rl) reg (d&3) holds out^T[d][mt*16+rl]
        int base = (mt << 8) + ((((d >> 2) << 4) + rl) << 2) + (d & 3);
#pragma unroll
        for (int w = 0; w < NW; ++w) s += red[(w << 10) + base];
        o[d] = s;
      }
      float m = 0.f;
#pragma unroll
      for (int k = 0; k < 8; ++k) m += o[k];
      m *= 0.125f;
      float var = 0.f;
#pragma unroll
      for (int k = 0; k < 8; ++k) { float dm = o[k] - m; var += dm * dm; }
      float rs = rsqrtf(var * 0.125f + 1e-5f);
#pragma unroll
      for (int k = 0; k < 8; ++k) X[r][k] = (o[k] - m) * rs * g[k] + bb[k];
    }
    __syncthreads();
  };

  // FFN computing ONLY row t (placed at column 0 of tile 0; the MFMA k-sum
  // is column-independent so the row-t result is bit-identical to full ffn).
  auto ffn_row = [&](const short* wsL, const float* b2, const float* g,
                     const float* bb, int t) {
    const short* pb = wsL + (wave * BPW) * 2048;
    short8 a0  = *(const short8*)(pb + lane * 8);
    short8 a1  = *(const short8*)(pb + 512 + lane * 8);
    short8 w2h = *(const short8*)(pb + 1024 + lane * 8);
    short8 w2l = *(const short8*)(pb + 1536 + lane * 8);

    short8 bx = zero8;
    if (gg == 3) { bx[0] = (short)0x3F80; bx[1] = (short)0x3F80; }
    else if (rr == 0) {
      float4 A = *(const float4*)&X[t][0];
      float4 Bv = *(const float4*)&X[t][4];
      unsigned u0 = cvtpk(A.x, A.y), u1 = cvtpk(A.z, A.w);
      unsigned u2 = cvtpk(Bv.x, Bv.y), u3 = cvtpk(Bv.z, Bv.w);
      if (gg == 2) {
        unsigned l0 = cvtpk(A.x - lo2f(u0), A.y - hi2f(u0));
        unsigned l1 = cvtpk(A.z - lo2f(u1), A.w - hi2f(u1));
        unsigned l2 = cvtpk(Bv.x - lo2f(u2), Bv.y - hi2f(u2));
        unsigned l3 = cvtpk(Bv.z - lo2f(u3), Bv.w - hi2f(u3));
        bx = pack4(l0, l1, l2, l3);
      } else {
        bx = pack4(u0, u1, u2, u3);
      }
    }

    floatx4 acc = zf4;
    for (int blkI = 0; blkI < BPW; ++blkI) {
      short8 na0 = zero8, na1 = zero8, nw2h = zero8, nw2l = zero8;
      if (blkI + 1 < BPW) {
        const short* pn = pb + (blkI + 1) * 2048;
        na0  = *(const short8*)(pn + lane * 8);
        na1  = *(const short8*)(pn + 512 + lane * 8);
        nw2h = *(const short8*)(pn + 1024 + lane * 8);
        nw2l = *(const short8*)(pn + 1536 + lane * 8);
      }
      floatx4 h0 = mfma16(a0, bx, zf4);
      floatx4 h1 = mfma16(a1, bx, zf4);
      float v0 = fmaxf(h0[0], 0.f), v1 = fmaxf(h0[1], 0.f);
      float v2 = fmaxf(h0[2], 0.f), v3 = fmaxf(h0[3], 0.f);
      float v4 = fmaxf(h1[0], 0.f), v5 = fmaxf(h1[1], 0.f);
      float v6 = fmaxf(h1[2], 0.f), v7 = fmaxf(h1[3], 0.f);
      unsigned u0 = cvtpk(v0, v1), u1 = cvtpk(v2, v3);
      unsigned u2 = cvtpk(v4, v5), u3 = cvtpk(v6, v7);
      unsigned l0 = cvtpk(v0 - lo2f(u0), v1 - hi2f(u0));
      unsigned l1 = cvtpk(v2 - lo2f(u1), v3 - hi2f(u1));
      unsigned l2 = cvtpk(v4 - lo2f(u2), v5 - hi2f(u2));
      unsigned l3 = cvtpk(v6 - lo2f(u3), v7 - hi2f(u3));
      short8 ah = pack4(u0, u1, u2, u3);
      short8 al = pack4(l0, l1, l2, l3);
      acc = mfma16(w2h, ah, acc);
      acc = mfma16(w2h, al, acc);
      acc = mfma16(w2l, ah, acc);
      a0 = na0; a1 = na1; w2h = nw2h; w2l = nw2l;
    }

    *(floatx4*)&red[(wave << 10) + (lane << 2)] = acc;
    __syncthreads();
    if (tid == 0) {
      float o[8];
#pragma unroll
      for (int d = 0; d < 8; ++d) {
        float s = X[t][d] + b2[d];
        int base = ((d >> 2) << 6) + (d & 3);   // lane (gg=d>>2, rr=0) reg d&3
#pragma unroll
        for (int w = 0; w < NW; ++w) s += red[(w << 10) + base];
        o[d] = s;
      }
      float m = 0.f;
#pragma unroll
      for (int k = 0; k < 8; ++k) m += o[k];
      m *= 0.125f;
      float var = 0.f;
#pragma unroll
      for (int k = 0; k < 8; ++k) { float dm = o[k] - m; var += dm * dm; }
      float rs = rsqrtf(var * 0.125f + 1e-5f);
#pragma unroll
      for (int k = 0; k < 8; ++k) X[t][k] = (o[k] - m) * rs * g[k] + bb[k];
    }
    __syncthreads();
  };

  // ---------------- the 60-step scan ----------------
  for (int t = 0; t < T; ++t) {
    const int R = t + 1;
    const int Mt = (R + 15) >> 4;

    for (int o = tid; o < 512; o += NT) {
      int r = o >> 3, d = o & 7;
      X[r][d] = (r < R) ? buf[r][d] : 0.f;
    }
    __syncthreads();

    // encoder: 6 layers, keys <= t
    for (int li = 0; li < 6; ++li) {
      mha(li, X, false, R, lnp[li * 4 + 0], lnp[li * 4 + 1]);
      ffn(ws + li * LSTR, b2all[li], lnp[li * 4 + 2], lnp[li * 4 + 3], R, Mt);
    }
    ln_rows(X, X, lnp[24], lnp[25], R);
    __syncthreads();
    for (int o = tid; o < 512; o += NT) {
      int r = o >> 3, d = o & 7;
      if (r < R) Mem[r][d] = X[r][d];
      X[r][d] = (r < R) ? buf[r][d] : 0.f;
    }
    __syncthreads();

    // decoder layer 1: full (its rows are layer-2 self-attn keys)
    mha(6, X,   true,  R, lnp[26], lnp[27]);
    mha(7, Mem, false, R, lnp[28], lnp[29]);
    ffn(ws + 6 * LSTR, b2all[6], lnp[30], lnp[31], R, Mt);

    // decoder layer 2: ONLY row t is ever consumed downstream
    mha_row(8, X,   R, t, lnp[32], lnp[33]);
    mha_row(9, Mem, R, t, lnp[34], lnp[35]);
    ffn_row(ws + 7 * LSTR, b2all[7], lnp[36], lnp[37], t);

    // final LN (row t) + st = y[t] @ fc_W^T + fc_b -> out; embed to buf[t+1]
    if (tid == 0) {
      float o[8];
#pragma unroll
      for (int k = 0; k < 8; ++k) o[k] = X[t][k];
      float m = 0.f;
#pragma unroll
      for (int k = 0; k < 8; ++k) m += o[k];
      m *= 0.125f;
      float v = 0.f;
#pragma unroll
      for (int k = 0; k < 8; ++k) { float dm = o[k] - m; v += dm * dm; }
      float rs = rsqrtf(v * 0.125f + 1e-5f);
#pragma unroll
      for (int k = 0; k < 8; ++k) X[t][k] = (o[k] - m) * rs * lnp[38][k] + lnp[39][k];
    }
    __syncthreads();
    if (tid < SD) {
      float s = fcbv[tid];
#pragma unroll
      for (int k = 0; k < 8; ++k) s += X[t][k] * fcw[tid][k];
      stv[tid] = s;
      P.out[(b * T + t) * SD + tid] = s;
    }
    __syncthreads();
    if (t + 1 < T && tid < D) {
      float s = embbv[tid];
#pragma unroll
      for (int k = 0; k < SD; ++k) s += stv[k] * embw[tid][k];
      buf[t + 1][tid] = s;
    }
    __syncthreads();
  }
}

extern "C" void kernel_launch(void* const* d_in, const int* in_sizes, int n_in,
                              void* d_out, int out_size, void* d_ws, size_t ws_size,
                              hipStream_t stream) {
  (void)in_sizes; (void)n_in; (void)ws_size; (void)out_size;
  Params P;
  for (int i = 0; i < 39; ++i) P.in[i] = (const float*)d_in[i];
  P.out = (float*)d_out;
  short* ws = (short*)d_ws;   // 8 layers * 256KB = 2MB of packed fragments
  repack_kernel<<<dim3(8 * NBLK), dim3(64), 0, stream>>>(P, ws);
  tdec_kernel<<<dim3(128), dim3(NT), 0, stream>>>(P, ws);
}